// Round 1
// baseline (762.233 us; speedup 1.0000x reference)
//
#include <hip/hip_runtime.h>

#define B_    4
#define H_    16
#define S_    2048
#define D_    64
#define QBLK  64
#define KBLK  64
#define NW    4
#define SCALE 0.125f
#define QPAD  72   // 64 + 8 bf16 pad: 16B-aligned rows, 2-way banks max
#define PPAD  68   // 64 + 4 fp32 pad: 16B-aligned rows, 2-way banks max

typedef __bf16 bf16x8 __attribute__((ext_vector_type(8)));
typedef __bf16 bf16x4 __attribute__((ext_vector_type(4)));
typedef float  f32x4  __attribute__((ext_vector_type(4)));

__global__ __launch_bounds__(256, 3)
void sdpa_kernel(const float* __restrict__ Q, const float* __restrict__ K,
                 const float* __restrict__ V, const int* __restrict__ mask,
                 float* __restrict__ ctx_out, float* __restrict__ attn_out)
{
    __shared__ __align__(16) __bf16 Qs[QBLK][QPAD];
    __shared__ __align__(16) __bf16 Ks[KBLK][QPAD];
    __shared__ __align__(16) __bf16 Vt[D_][QPAD];      // V transposed: [d][k]
    __shared__ __align__(16) float  Ps[NW][16][PPAD];  // per-wave P strip
    __shared__ float maskf[S_];                        // 1.0 = keep, 0.0 = masked

    const int tid   = threadIdx.x;
    const int lane  = tid & 63;
    const int wid   = tid >> 6;
    const int l15   = lane & 15;
    const int lhi   = lane >> 4;     // 0..3
    const int kbase = lhi * 8;

    // XCD-aware bijective swizzle (grid = 2048, 2048 % 8 == 0)
    const int orig = blockIdx.x;
    const int cpx  = gridDim.x >> 3;
    const int bid  = (orig & 7) * cpx + (orig >> 3);

    const int qt = bid & 31;         // S_/QBLK = 32
    const int bh = bid >> 5;         // 0..63
    const int b  = bh >> 4;          // H_=16

    const float* Qp = Q + ((size_t)bh * S_ + (size_t)qt * QBLK) * D_;
    const float* Kp = K + (size_t)bh * S_ * D_;
    const float* Vp = V + (size_t)bh * S_ * D_;
    const int*   mp = mask + b * S_;

    // stage mask flags (true -> -1e9 -> attn 0  => flag 0)
    for (int i = tid; i < S_; i += 256)
        maskf[i] = mp[i] ? 0.0f : 1.0f;

    // stage Q tile fp32->bf16
    for (int i = tid; i < (QBLK * D_) / 4; i += 256) {
        int r = i >> 4;
        int c = (i & 15) << 2;
        float4 v = reinterpret_cast<const float4*>(Qp)[i];
        bf16x4 w = { (__bf16)v.x, (__bf16)v.y, (__bf16)v.z, (__bf16)v.w };
        *reinterpret_cast<bf16x4*>(&Qs[r][c]) = w;
    }
    __syncthreads();

    // Q A-fragments: rows wid*16 + (lane&15), k = kstep*32 + (lane>>4)*8 + j
    bf16x8 aQ[2];
    {
        int qr = wid * 16 + l15;
        aQ[0] = *reinterpret_cast<const bf16x8*>(&Qs[qr][kbase]);
        aQ[1] = *reinterpret_cast<const bf16x8*>(&Qs[qr][32 + kbase]);
    }

    // ---------------- pass 1: row sums l ----------------
    float lsum[4] = {0.f, 0.f, 0.f, 0.f};
    for (int kt = 0; kt < S_ / KBLK; ++kt) {
        __syncthreads();
        const float* Kt = Kp + (size_t)kt * KBLK * D_;
        for (int i = tid; i < (KBLK * D_) / 4; i += 256) {
            int r = i >> 4;
            int c = (i & 15) << 2;
            float4 v = reinterpret_cast<const float4*>(Kt)[i];
            bf16x4 w = { (__bf16)v.x, (__bf16)v.y, (__bf16)v.z, (__bf16)v.w };
            *reinterpret_cast<bf16x4*>(&Ks[r][c]) = w;
        }
        __syncthreads();
        #pragma unroll
        for (int sub = 0; sub < KBLK / 16; ++sub) {
            bf16x8 b0 = *reinterpret_cast<const bf16x8*>(&Ks[sub * 16 + l15][kbase]);
            bf16x8 b1 = *reinterpret_cast<const bf16x8*>(&Ks[sub * 16 + l15][32 + kbase]);
            f32x4 acc = {0.f, 0.f, 0.f, 0.f};
            acc = __builtin_amdgcn_mfma_f32_16x16x32_bf16(aQ[0], b0, acc, 0, 0, 0);
            acc = __builtin_amdgcn_mfma_f32_16x16x32_bf16(aQ[1], b1, acc, 0, 0, 0);
            float flag = maskf[kt * KBLK + sub * 16 + l15];
            #pragma unroll
            for (int r = 0; r < 4; ++r)
                lsum[r] += flag * __expf(acc[r] * SCALE);
        }
    }
    // reduce across the 16 lanes holding the same 4 rows
    #pragma unroll
    for (int r = 0; r < 4; ++r) {
        lsum[r] += __shfl_xor(lsum[r], 1);
        lsum[r] += __shfl_xor(lsum[r], 2);
        lsum[r] += __shfl_xor(lsum[r], 4);
        lsum[r] += __shfl_xor(lsum[r], 8);
    }
    float rl[4];
    #pragma unroll
    for (int r = 0; r < 4; ++r) rl[r] = 1.0f / lsum[r];

    // ---------------- pass 2: attn write + PV ----------------
    const f32x4 vzero = {0.f, 0.f, 0.f, 0.f};
    f32x4 ctx[4];
    #pragma unroll
    for (int d = 0; d < 4; ++d) ctx[d] = vzero;

    const size_t attn_row0 = (size_t)bh * S_ + (size_t)qt * QBLK;

    for (int kt = 0; kt < S_ / KBLK; ++kt) {
        __syncthreads();
        const float* Kt    = Kp + (size_t)kt * KBLK * D_;
        const float* Vtile = Vp + (size_t)kt * KBLK * D_;
        for (int i = tid; i < (KBLK * D_) / 4; i += 256) {
            int r = i >> 4;
            int c = (i & 15) << 2;
            float4 v = reinterpret_cast<const float4*>(Kt)[i];
            bf16x4 w = { (__bf16)v.x, (__bf16)v.y, (__bf16)v.z, (__bf16)v.w };
            *reinterpret_cast<bf16x4*>(&Ks[r][c]) = w;
            float4 u = reinterpret_cast<const float4*>(Vtile)[i];
            Vt[c + 0][r] = (__bf16)u.x;
            Vt[c + 1][r] = (__bf16)u.y;
            Vt[c + 2][r] = (__bf16)u.z;
            Vt[c + 3][r] = (__bf16)u.w;
        }
        __syncthreads();

        // QK^T, normalize, store P strip to wave-private LDS
        #pragma unroll
        for (int sub = 0; sub < KBLK / 16; ++sub) {
            bf16x8 b0 = *reinterpret_cast<const bf16x8*>(&Ks[sub * 16 + l15][kbase]);
            bf16x8 b1 = *reinterpret_cast<const bf16x8*>(&Ks[sub * 16 + l15][32 + kbase]);
            f32x4 acc = {0.f, 0.f, 0.f, 0.f};
            acc = __builtin_amdgcn_mfma_f32_16x16x32_bf16(aQ[0], b0, acc, 0, 0, 0);
            acc = __builtin_amdgcn_mfma_f32_16x16x32_bf16(aQ[1], b1, acc, 0, 0, 0);
            float flag = maskf[kt * KBLK + sub * 16 + l15];
            #pragma unroll
            for (int r = 0; r < 4; ++r) {
                float p = flag * __expf(acc[r] * SCALE) * rl[r];
                Ps[wid][lhi * 4 + r][sub * 16 + l15] = p;
            }
        }
        // wave-private Ps: same-wave LDS ordering suffices (no barrier)

        // coalesced attn store: 16 rows x 64 cols fp32, float4
        #pragma unroll
        for (int it = 0; it < 4; ++it) {
            int idx = (it << 6) + lane;
            int r   = idx >> 4;
            int c   = (idx & 15) << 2;
            float4 v = *reinterpret_cast<float4*>(&Ps[wid][r][c]);
            size_t off = (attn_row0 + (size_t)(wid * 16 + r)) * S_ + (size_t)kt * KBLK + c;
            *reinterpret_cast<float4*>(&attn_out[off]) = v;
        }

        // PV: A-fragments from Ps (transpose via LDS), B from Vt
        bf16x8 aP[2];
        #pragma unroll
        for (int ks = 0; ks < 2; ++ks) {
            const float* src = &Ps[wid][l15][ks * 32 + kbase];
            f32x4 lo = *reinterpret_cast<const f32x4*>(src);
            f32x4 hi = *reinterpret_cast<const f32x4*>(src + 4);
            bf16x8 t;
            t[0] = (__bf16)lo[0]; t[1] = (__bf16)lo[1];
            t[2] = (__bf16)lo[2]; t[3] = (__bf16)lo[3];
            t[4] = (__bf16)hi[0]; t[5] = (__bf16)hi[1];
            t[6] = (__bf16)hi[2]; t[7] = (__bf16)hi[3];
            aP[ks] = t;
        }
        #pragma unroll
        for (int d = 0; d < 4; ++d) {
            bf16x8 b0 = *reinterpret_cast<const bf16x8*>(&Vt[d * 16 + l15][kbase]);
            bf16x8 b1 = *reinterpret_cast<const bf16x8*>(&Vt[d * 16 + l15][32 + kbase]);
            ctx[d] = __builtin_amdgcn_mfma_f32_16x16x32_bf16(aP[0], b0, ctx[d], 0, 0, 0);
            ctx[d] = __builtin_amdgcn_mfma_f32_16x16x32_bf16(aP[1], b1, ctx[d], 0, 0, 0);
        }
    }

    // write context: row = (lane>>4)*4 + r, col = d*16 + (lane&15)
    #pragma unroll
    for (int d = 0; d < 4; ++d) {
        #pragma unroll
        for (int r = 0; r < 4; ++r) {
            size_t row = attn_row0 + (size_t)(wid * 16 + lhi * 4 + r);
            ctx_out[row * D_ + d * 16 + l15] = ctx[d][r];
        }
    }
}

extern "C" void kernel_launch(void* const* d_in, const int* in_sizes, int n_in,
                              void* d_out, int out_size, void* d_ws, size_t ws_size,
                              hipStream_t stream) {
    const float* Q    = (const float*)d_in[0];
    const float* K    = (const float*)d_in[1];
    const float* V    = (const float*)d_in[2];
    const int*   mask = (const int*)d_in[3];

    float* ctx_out  = (float*)d_out;
    float* attn_out = (float*)d_out + (size_t)B_ * H_ * S_ * D_;

    dim3 grid(B_ * H_ * (S_ / QBLK));
    dim3 block(256);
    sdpa_kernel<<<grid, block, 0, stream>>>(Q, K, V, mask, ctx_out, attn_out);
}